// Round 10
// baseline (149.184 us; speedup 1.0000x reference)
//
#include <hip/hip_runtime.h>
#include <hip/hip_bf16.h>
#include <math.h>

#define VOCAB 100000
#define INPUT_DIM 100
#define HIDDEN_DIM 10
#define BATCH 1024
#define SEQ 512

#define ROWS_PER_BLK 64
#define LDS_PITCH 101  // 101 mod 32 = 5 (odd) -> conflict-free lane access

// ---------------------------------------------------------------------------
// Kernel A v2: proj[v][i] = dot(emb[v], W_ih[i]) + b_ih[i] + b_hh[i]
// COALESCED: each 256-thread block stages 64 emb rows into LDS with fully
// linear global loads (25 contiguous dwords/thread; 64 lanes = 256 B = 4
// cache lines per instr), then computes from LDS.
// Row pitch 101 floats: lane l reads lds[l*101+k]; l*101 mod 32 = l*5 mod 32,
// 5 odd -> 32 banks bijective over 32 lanes, 2 lanes/bank over 64 = free.
// Wave q in {0..3} computes i = q, q+4, q+8(<10): wave-uniform i -> W row
// via scalar cache. Biases folded into proj (kernel B depends on this).
// Memory-bound: 40 MB read (coalesced) + 4 MB write -> ~8 us.
// ---------------------------------------------------------------------------
__global__ __launch_bounds__(256) void proj_kernel(
    const float* __restrict__ emb, const float* __restrict__ W_ih,
    const float* __restrict__ b_ih, const float* __restrict__ b_hh,
    float* __restrict__ proj) {
  __shared__ float se[ROWS_PER_BLK * LDS_PITCH];  // 25.9 KB

  const int t = threadIdx.x;
  const size_t base = (size_t)blockIdx.x * (ROWS_PER_BLK * INPUT_DIM);
  const size_t TOT = (size_t)VOCAB * INPUT_DIM;

  // Stage 64 rows: linear index n = t + 256*l over 6400 floats.
#pragma unroll
  for (int l = 0; l < 25; ++l) {
    int n = t + 256 * l;
    size_t g = base + n;
    float val = (g < TOT) ? emb[g] : 0.f;
    int r = n / 100;  // compiler -> mul_hi magic
    int k = n - r * 100;
    se[r * LDS_PITCH + k] = val;
  }
  __syncthreads();

  const int row = t & 63;          // lane
  const int q = t >> 6;            // wave id, uniform per wave
  const int v = blockIdx.x * ROWS_PER_BLK + row;

  const float* W0 = W_ih + q * INPUT_DIM;        // i = q
  const float* W1 = W_ih + (q + 4) * INPUT_DIM;  // i = q+4
  const float* W2 = W_ih + ((q < 2) ? (q + 8) : q) * INPUT_DIM;  // i = q+8

  float acc0 = b_ih[q] + b_hh[q];
  float acc1 = b_ih[q + 4] + b_hh[q + 4];
  float acc2 = (q < 2) ? (b_ih[q + 8] + b_hh[q + 8]) : 0.f;

  const float* er = se + row * LDS_PITCH;
#pragma unroll
  for (int k = 0; k < INPUT_DIM; ++k) {
    float e = er[k];
    acc0 = fmaf(e, W0[k], acc0);  // W*[k] wave-uniform -> s_load
    acc1 = fmaf(e, W1[k], acc1);
    acc2 = fmaf(e, W2[k], acc2);
  }

  if (v < VOCAB) {
    float* pv = proj + (size_t)v * HIDDEN_DIM;
    pv[q] = acc0;
    pv[q + 4] = acc1;
    if (q < 2) pv[q + 8] = acc2;
  }
}

// ---------------------------------------------------------------------------
// Kernel B: the 512-step recurrence. One WAVE per batch element (1024 waves
// = 1/SIMD chip-wide). Lane i<10 owns h[i]; h[j] broadcast via v_readlane.
// x indices staged into LDS once per wave; per-phase index reads on LGKM
// counter so the VM queue carries only proj gathers (3 phases in flight).
// UNCHANGED from round 8 for clean attribution of the kernel-A fix.
// ---------------------------------------------------------------------------
__global__ __launch_bounds__(256, 1) void scan_kernel(
    const int* __restrict__ x, const float* __restrict__ proj,
    const float* __restrict__ W_hh, const float* __restrict__ W_fc,
    const float* __restrict__ b_fc, float* __restrict__ out) {
  __shared__ int sIdx[4][SEQ];  // 8 KB: per-wave index row

  int lane = threadIdx.x & 63;
  int widx = threadIdx.x >> 6;  // wave within block, 0..3
  int b = __builtin_amdgcn_readfirstlane((int)(blockIdx.x * 4 + widx));
  int i = (lane < HIDDEN_DIM) ? lane : 0;  // idle lanes shadow row 0

  float Wr[HIDDEN_DIM];
#pragma unroll
  for (int j = 0; j < HIDDEN_DIM; ++j) Wr[j] = W_hh[i * HIDDEN_DIM + j];
  float wfc = (lane < HIDDEN_DIM) ? W_fc[lane] : 0.f;

  // Stage this wave's 512 indices into LDS (coalesced, once).
  const int4* xb4 = (const int4*)(x + (size_t)b * SEQ);
  int4* s4 = (int4*)(sIdx[widx]);
  s4[lane] = xb4[lane];            // ints 0..255
  s4[64 + lane] = xb4[64 + lane];  // ints 256..511
  // No barrier needed: each wave reads only LDS it wrote itself.

  const float* projLane = proj + i;  // per-lane base
  float h = 0.f;

#define LOADIDX(Q0, Q1, base)                              \
  {                                                        \
    int bc_ = (base) <= (SEQ - 8) ? (base) : (SEQ - 8);    \
    Q0 = s4[bc_ >> 2];                                     \
    Q1 = s4[(bc_ >> 2) + 1];                               \
  }
#define GATHER(P, Q0, Q1)                                  \
  P[0] = projLane[(unsigned)Q0.x * 10u];                   \
  P[1] = projLane[(unsigned)Q0.y * 10u];                   \
  P[2] = projLane[(unsigned)Q0.z * 10u];                   \
  P[3] = projLane[(unsigned)Q0.w * 10u];                   \
  P[4] = projLane[(unsigned)Q1.x * 10u];                   \
  P[5] = projLane[(unsigned)Q1.y * 10u];                   \
  P[6] = projLane[(unsigned)Q1.z * 10u];                   \
  P[7] = projLane[(unsigned)Q1.w * 10u];
#define COMPUTE(P)                                         \
  _Pragma("unroll") for (int u = 0; u < 8; ++u) {          \
    float hj[HIDDEN_DIM];                                  \
    _Pragma("unroll") for (int j = 0; j < HIDDEN_DIM; ++j) \
      hj[j] = __uint_as_float(                             \
          __builtin_amdgcn_readlane(__float_as_uint(h), j)); \
    float a0 = fmaf(Wr[0], hj[0], P[u]);                   \
    float a1 = Wr[1] * hj[1];                              \
    a0 = fmaf(Wr[2], hj[2], a0);                           \
    a1 = fmaf(Wr[3], hj[3], a1);                           \
    a0 = fmaf(Wr[4], hj[4], a0);                           \
    a1 = fmaf(Wr[5], hj[5], a1);                           \
    a0 = fmaf(Wr[6], hj[6], a0);                           \
    a1 = fmaf(Wr[7], hj[7], a1);                           \
    a0 = fmaf(Wr[8], hj[8], a0);                           \
    a1 = fmaf(Wr[9], hj[9], a1);                           \
    h = fmaxf(a0 + a1, 0.f);                               \
  }

  int4 Ia0, Ia1, Ib0, Ib1, Ic0, Ic1, Id0, Id1;
  float pA[8], pB[8], pC[8], pD[8];

  LOADIDX(Ia0, Ia1, 0) LOADIDX(Ib0, Ib1, 8) LOADIDX(Ic0, Ic1, 16)
  GATHER(pA, Ia0, Ia1) GATHER(pB, Ib0, Ib1) GATHER(pC, Ic0, Ic1)
  LOADIDX(Id0, Id1, 24)

  for (int tt = 0; tt < SEQ; tt += 32) {
    GATHER(pD, Id0, Id1) LOADIDX(Ia0, Ia1, tt + 32) COMPUTE(pA)
    GATHER(pA, Ia0, Ia1) LOADIDX(Ib0, Ib1, tt + 40) COMPUTE(pB)
    GATHER(pB, Ib0, Ib1) LOADIDX(Ic0, Ic1, tt + 48) COMPUTE(pC)
    GATHER(pC, Ic0, Ic1) LOADIDX(Id0, Id1, tt + 56) COMPUTE(pD)
  }
#undef LOADIDX
#undef GATHER
#undef COMPUTE

  // FC + sigmoid over lanes 0..9.
  float prod = wfc * h;
  float z = 0.f;
#pragma unroll
  for (int j = 0; j < HIDDEN_DIM; ++j)
    z += __uint_as_float(__builtin_amdgcn_readlane(__float_as_uint(prod), j));
  if (lane == 0) out[b] = 1.f / (1.f + expf(-(z + b_fc[0])));
}

extern "C" void kernel_launch(void* const* d_in, const int* in_sizes, int n_in,
                              void* d_out, int out_size, void* d_ws, size_t ws_size,
                              hipStream_t stream) {
  const int*   x    = (const int*)d_in[0];
  const float* emb  = (const float*)d_in[1];
  const float* W_ih = (const float*)d_in[2];
  const float* b_ih = (const float*)d_in[3];
  const float* W_hh = (const float*)d_in[4];
  const float* b_hh = (const float*)d_in[5];
  const float* W_fc = (const float*)d_in[6];
  const float* b_fc = (const float*)d_in[7];
  float* out = (float*)d_out;

  float* proj = (float*)d_ws;  // VOCAB*HIDDEN_DIM*4 = 4 MB scratch

  int blocksA = (VOCAB + ROWS_PER_BLK - 1) / ROWS_PER_BLK;  // 1563
  proj_kernel<<<blocksA, 256, 0, stream>>>(emb, W_ih, b_ih, b_hh, proj);

  int blocksB = BATCH / 4;  // 4 waves/block, one wave per batch element
  scan_kernel<<<blocksB, 256, 0, stream>>>(x, proj, W_hh, W_fc, b_fc, out);
}

// Round 11
// 138.309 us; speedup vs baseline: 1.0786x; 1.0786x over previous
//
#include <hip/hip_runtime.h>
#include <hip/hip_bf16.h>
#include <math.h>

#define VOCAB 100000
#define INPUT_DIM 100
#define HIDDEN_DIM 10
#define BATCH 1024
#define SEQ 512

#define ROWS_PER_BLK 64
#define LDS_PITCH 101  // lane l, elem k -> bank (5l+k)%32: bijective, free

// ---------------------------------------------------------------------------
// Kernel A v3: proj[v][i] = dot(emb[v], W_ih[i]) + b_ih[i] + b_hh[i]
// r10 lesson: W loads with q = t>>6 were NOT provably wave-uniform -> 300
// per-lane global_load_dword per thread -> stall-bound (VALUBusy 9%).
// Fix: stage W_ih (4 KB) into LDS too. Inner loop reads e per-lane
// (pitch-101, conflict-free) and w as wave-uniform LDS broadcasts (free).
// ZERO global loads in the inner loop; everything on the LGKM path.
// Issue cost ~700 instr/wave; chip-wide ~3 us; HBM floor ~7 us.
// ---------------------------------------------------------------------------
__global__ __launch_bounds__(256) void proj_kernel(
    const float* __restrict__ emb, const float* __restrict__ W_ih,
    const float* __restrict__ b_ih, const float* __restrict__ b_hh,
    float* __restrict__ proj) {
  __shared__ float se[ROWS_PER_BLK * LDS_PITCH];   // 25.9 KB
  __shared__ float sW[HIDDEN_DIM * INPUT_DIM];     // 4 KB

  const int t = threadIdx.x;

  // Stage W_ih: 1000 contiguous floats, coalesced.
  for (int n = t; n < HIDDEN_DIM * INPUT_DIM; n += 256) sW[n] = W_ih[n];

  // Stage 64 emb rows: linear index n = t + 256*l over 6400 floats.
  const size_t base = (size_t)blockIdx.x * (ROWS_PER_BLK * INPUT_DIM);
  const size_t TOT = (size_t)VOCAB * INPUT_DIM;
#pragma unroll
  for (int l = 0; l < 25; ++l) {
    int n = t + 256 * l;
    size_t g = base + n;
    float val = (g < TOT) ? emb[g] : 0.f;
    int r = n / 100;  // magic-mul
    int k = n - r * 100;
    se[r * LDS_PITCH + k] = val;
  }
  __syncthreads();

  const int row = t & 63;  // lane = emb row within block
  const int q = t >> 6;    // wave id: computes i = q, q+4, (q+8 if q<2)
  const int v = blockIdx.x * ROWS_PER_BLK + row;
  const int iq2 = (q < 2) ? (q + 8) : q;  // dummy for q>=2 (never stored)

  float acc0 = b_ih[q] + b_hh[q];
  float acc1 = b_ih[q + 4] + b_hh[q + 4];
  float acc2 = b_ih[iq2] + b_hh[iq2];

  const float* er = se + row * LDS_PITCH;
  const float* w0 = sW + q * INPUT_DIM;        // uniform addr -> broadcast
  const float* w1 = sW + (q + 4) * INPUT_DIM;  // uniform addr -> broadcast
  const float* w2 = sW + iq2 * INPUT_DIM;      // uniform addr -> broadcast

#pragma unroll
  for (int k = 0; k < INPUT_DIM; ++k) {
    float e = er[k];
    acc0 = fmaf(e, w0[k], acc0);
    acc1 = fmaf(e, w1[k], acc1);
    acc2 = fmaf(e, w2[k], acc2);
  }

  if (v < VOCAB) {
    float* pv = proj + (size_t)v * HIDDEN_DIM;
    pv[q] = acc0;
    pv[q + 4] = acc1;
    if (q < 2) pv[q + 8] = acc2;
  }
}

// ---------------------------------------------------------------------------
// Kernel B: the 512-step recurrence. One WAVE per batch element (1024 waves
// = 1/SIMD chip-wide). Lane i<10 owns h[i]; h[j] broadcast via v_readlane.
// x indices staged into LDS once per wave; per-phase index reads on LGKM
// counter so the VM queue carries only proj gathers (3 phases in flight).
// UNCHANGED from rounds 8-10 for clean attribution of the kernel-A fix.
// ---------------------------------------------------------------------------
__global__ __launch_bounds__(256, 1) void scan_kernel(
    const int* __restrict__ x, const float* __restrict__ proj,
    const float* __restrict__ W_hh, const float* __restrict__ W_fc,
    const float* __restrict__ b_fc, float* __restrict__ out) {
  __shared__ int sIdx[4][SEQ];  // 8 KB: per-wave index row

  int lane = threadIdx.x & 63;
  int widx = threadIdx.x >> 6;  // wave within block, 0..3
  int b = __builtin_amdgcn_readfirstlane((int)(blockIdx.x * 4 + widx));
  int i = (lane < HIDDEN_DIM) ? lane : 0;  // idle lanes shadow row 0

  float Wr[HIDDEN_DIM];
#pragma unroll
  for (int j = 0; j < HIDDEN_DIM; ++j) Wr[j] = W_hh[i * HIDDEN_DIM + j];
  float wfc = (lane < HIDDEN_DIM) ? W_fc[lane] : 0.f;

  // Stage this wave's 512 indices into LDS (coalesced, once).
  const int4* xb4 = (const int4*)(x + (size_t)b * SEQ);
  int4* s4 = (int4*)(sIdx[widx]);
  s4[lane] = xb4[lane];            // ints 0..255
  s4[64 + lane] = xb4[64 + lane];  // ints 256..511
  // No barrier needed: each wave reads only LDS it wrote itself.

  const float* projLane = proj + i;  // per-lane base
  float h = 0.f;

#define LOADIDX(Q0, Q1, base)                              \
  {                                                        \
    int bc_ = (base) <= (SEQ - 8) ? (base) : (SEQ - 8);    \
    Q0 = s4[bc_ >> 2];                                     \
    Q1 = s4[(bc_ >> 2) + 1];                               \
  }
#define GATHER(P, Q0, Q1)                                  \
  P[0] = projLane[(unsigned)Q0.x * 10u];                   \
  P[1] = projLane[(unsigned)Q0.y * 10u];                   \
  P[2] = projLane[(unsigned)Q0.z * 10u];                   \
  P[3] = projLane[(unsigned)Q0.w * 10u];                   \
  P[4] = projLane[(unsigned)Q1.x * 10u];                   \
  P[5] = projLane[(unsigned)Q1.y * 10u];                   \
  P[6] = projLane[(unsigned)Q1.z * 10u];                   \
  P[7] = projLane[(unsigned)Q1.w * 10u];
#define COMPUTE(P)                                         \
  _Pragma("unroll") for (int u = 0; u < 8; ++u) {          \
    float hj[HIDDEN_DIM];                                  \
    _Pragma("unroll") for (int j = 0; j < HIDDEN_DIM; ++j) \
      hj[j] = __uint_as_float(                             \
          __builtin_amdgcn_readlane(__float_as_uint(h), j)); \
    float a0 = fmaf(Wr[0], hj[0], P[u]);                   \
    float a1 = Wr[1] * hj[1];                              \
    a0 = fmaf(Wr[2], hj[2], a0);                           \
    a1 = fmaf(Wr[3], hj[3], a1);                           \
    a0 = fmaf(Wr[4], hj[4], a0);                           \
    a1 = fmaf(Wr[5], hj[5], a1);                           \
    a0 = fmaf(Wr[6], hj[6], a0);                           \
    a1 = fmaf(Wr[7], hj[7], a1);                           \
    a0 = fmaf(Wr[8], hj[8], a0);                           \
    a1 = fmaf(Wr[9], hj[9], a1);                           \
    h = fmaxf(a0 + a1, 0.f);                               \
  }

  int4 Ia0, Ia1, Ib0, Ib1, Ic0, Ic1, Id0, Id1;
  float pA[8], pB[8], pC[8], pD[8];

  LOADIDX(Ia0, Ia1, 0) LOADIDX(Ib0, Ib1, 8) LOADIDX(Ic0, Ic1, 16)
  GATHER(pA, Ia0, Ia1) GATHER(pB, Ib0, Ib1) GATHER(pC, Ic0, Ic1)
  LOADIDX(Id0, Id1, 24)

  for (int tt = 0; tt < SEQ; tt += 32) {
    GATHER(pD, Id0, Id1) LOADIDX(Ia0, Ia1, tt + 32) COMPUTE(pA)
    GATHER(pA, Ia0, Ia1) LOADIDX(Ib0, Ib1, tt + 40) COMPUTE(pB)
    GATHER(pB, Ib0, Ib1) LOADIDX(Ic0, Ic1, tt + 48) COMPUTE(pC)
    GATHER(pC, Ic0, Ic1) LOADIDX(Id0, Id1, tt + 56) COMPUTE(pD)
  }
#undef LOADIDX
#undef GATHER
#undef COMPUTE

  // FC + sigmoid over lanes 0..9.
  float prod = wfc * h;
  float z = 0.f;
#pragma unroll
  for (int j = 0; j < HIDDEN_DIM; ++j)
    z += __uint_as_float(__builtin_amdgcn_readlane(__float_as_uint(prod), j));
  if (lane == 0) out[b] = 1.f / (1.f + expf(-(z + b_fc[0])));
}

extern "C" void kernel_launch(void* const* d_in, const int* in_sizes, int n_in,
                              void* d_out, int out_size, void* d_ws, size_t ws_size,
                              hipStream_t stream) {
  const int*   x    = (const int*)d_in[0];
  const float* emb  = (const float*)d_in[1];
  const float* W_ih = (const float*)d_in[2];
  const float* b_ih = (const float*)d_in[3];
  const float* W_hh = (const float*)d_in[4];
  const float* b_hh = (const float*)d_in[5];
  const float* W_fc = (const float*)d_in[6];
  const float* b_fc = (const float*)d_in[7];
  float* out = (float*)d_out;

  float* proj = (float*)d_ws;  // VOCAB*HIDDEN_DIM*4 = 4 MB scratch

  int blocksA = (VOCAB + ROWS_PER_BLK - 1) / ROWS_PER_BLK;  // 1563
  proj_kernel<<<blocksA, 256, 0, stream>>>(emb, W_ih, b_ih, b_hh, proj);

  int blocksB = BATCH / 4;  // 4 waves/block, one wave per batch element
  scan_kernel<<<blocksB, 256, 0, stream>>>(x, proj, W_hh, W_fc, b_fc, out);
}